// Round 7
// baseline (436.593 us; speedup 1.0000x reference)
//
#include <hip/hip_runtime.h>
#include <hip/hip_bf16.h>
#include <cstdint>
#include <cstddef>

using bf16 = __hip_bfloat16;
using short4v = __attribute__((ext_vector_type(4))) short;  // 4 bf16 (2 VGPRs)
using short8 = __attribute__((ext_vector_type(8))) short;   // 8 bf16 (4 VGPRs)
using floatx4 = __attribute__((ext_vector_type(4))) float;  // MFMA C/D frag

#define MFMA_BF16(A, B, C) __builtin_amdgcn_mfma_f32_16x16x32_bf16((A), (B), (C), 0, 0, 0)

__device__ inline short bf16_bits(float x) {
  bf16 v = __float2bfloat16(x);
  short r;
  __builtin_memcpy(&r, &v, 2);
  return r;
}

__device__ inline void store_c(bf16* p, float v) { *p = __float2bfloat16(v); }
__device__ inline void store_c(float* p, float v) { *p = v; }

// ---------------------------------------------------------------------------
// f32 -> bf16 bulk convert (RNE). 8 elements/thread, 16B stores.
// ---------------------------------------------------------------------------
__global__ __launch_bounds__(256) void f32_to_bf16_kernel(
    const float* __restrict__ src, bf16* __restrict__ dst, int n8) {
  const int i = blockIdx.x * 256 + threadIdx.x;
  if (i >= n8) return;
  const float4 a = ((const float4*)src)[2 * i];
  const float4 b = ((const float4*)src)[2 * i + 1];
  short8 r;
  r[0] = bf16_bits(a.x); r[1] = bf16_bits(a.y); r[2] = bf16_bits(a.z); r[3] = bf16_bits(a.w);
  r[4] = bf16_bits(b.x); r[5] = bf16_bits(b.y); r[6] = bf16_bits(b.z); r[7] = bf16_bits(b.w);
  *(short8*)(dst + (size_t)i * 8) = r;
}

// ---------------------------------------------------------------------------
// GEMM (m97 structure): C[m,n] = sum_k A[m,k]*B[n,k], A,B row-major bf16,
// row stride K; C row-major stride ldc. Tile 128x128, BK=64, 4 waves (2x2).
// global_load_lds width=16 staging with XOR chunk swizzle.
// vT redirect (r6, proven): v-region column tiles (tn%6 >= 4) store
// pre-TRANSPOSED V into vT[b][h][d][s] as packed 8B stores.
// ---------------------------------------------------------------------------
template <typename TC>
__global__ __launch_bounds__(256) void gemm_bt_async(
    const bf16* __restrict__ A, const bf16* __restrict__ B, TC* __restrict__ C,
    int ldc, int K, bf16* __restrict__ vT, int mpbase) {
  __shared__ bf16 As[128 * 64];
  __shared__ bf16 Bs[128 * 64];
  const int tid = threadIdx.x;
  const int lane = tid & 63;
  const int wave = tid >> 6;
  const int lrow = lane & 15;
  const int quad = lane >> 4;
  const int wm = (wave >> 1) * 64;
  const int wn = (wave & 1) * 64;
  const int tm = blockIdx.y * 128;
  const int tn = blockIdx.x * 128;

  const int srow = tid >> 3;
  const int scl = tid & 7;

  floatx4 acc[4][4] = {};

  for (int k0 = 0; k0 < K; k0 += 64) {
    __syncthreads();
#pragma unroll
    for (int r = 0; r < 4; ++r) {
      const int row = r * 32 + srow;
      const int scg = scl ^ (row & 7);
      __builtin_amdgcn_global_load_lds(
          (const __attribute__((address_space(1))) void*)(A + (size_t)(tm + row) * K + k0 + scg * 8),
          (__attribute__((address_space(3))) void*)(As + row * 64 + scl * 8), 16, 0, 0);
    }
#pragma unroll
    for (int r = 0; r < 4; ++r) {
      const int row = r * 32 + srow;
      const int scg = scl ^ (row & 7);
      __builtin_amdgcn_global_load_lds(
          (const __attribute__((address_space(1))) void*)(B + (size_t)(tn + row) * K + k0 + scg * 8),
          (__attribute__((address_space(3))) void*)(Bs + row * 64 + scl * 8), 16, 0, 0);
    }
    __syncthreads();

#pragma unroll
    for (int kk = 0; kk < 2; ++kk) {
      short8 af[4], bfr[4];
#pragma unroll
      for (int i = 0; i < 4; ++i) {
        const int ra = wm + i * 16 + lrow;
        const int rb = wn + i * 16 + lrow;
        af[i] = *(const short8*)&As[ra * 64 + (((kk * 4 + quad) ^ (ra & 7)) * 8)];
        bfr[i] = *(const short8*)&Bs[rb * 64 + (((kk * 4 + quad) ^ (rb & 7)) * 8)];
      }
#pragma unroll
      for (int i = 0; i < 4; ++i)
#pragma unroll
        for (int j = 0; j < 4; ++j)
          acc[i][j] = MFMA_BF16(af[i], bfr[j], acc[i][j]);
    }
  }

  if (vT != nullptr && ((int)blockIdx.x % 6) >= 4) {
    // v-region tile: store transposed into vT[((b*16+h)*128+d)*2048 + s].
    const int mpl = (int)blockIdx.x / 6;
#pragma unroll
    for (int i = 0; i < 4; ++i)
#pragma unroll
      for (int j = 0; j < 4; ++j) {
        const int fl = tn + wn + j * 16 + lrow;   // col within this call's 3072
        const int sv = fl - mpl * 768 - 512;      // 0..255
        const int hh = mpbase + mpl * 2 + (sv >> 7);
        const int dd = sv & 127;
        const int m0 = tm + wm + i * 16 + quad * 4;  // 4 consecutive s rows
        const int bb = m0 >> 11;
        const int ss = m0 & 2047;
        short4v pv;
        pv[0] = bf16_bits(acc[i][j][0]); pv[1] = bf16_bits(acc[i][j][1]);
        pv[2] = bf16_bits(acc[i][j][2]); pv[3] = bf16_bits(acc[i][j][3]);
        *(short4v*)&vT[((size_t)(bb * 16 + hh) * 128 + dd) * 2048 + ss] = pv;
      }
  } else {
#pragma unroll
    for (int i = 0; i < 4; ++i)
#pragma unroll
      for (int j = 0; j < 4; ++j)
#pragma unroll
        for (int r = 0; r < 4; ++r) {
          const int row = tm + wm + i * 16 + quad * 4 + r;
          const int col = tn + wn + j * 16 + lrow;
          store_c(&C[(size_t)row * ldc + col], acc[i][j][r]);
        }
  }
}

// ---------------------------------------------------------------------------
// Mixed GEMM for the out-projection: A bf16 via global_load_lds; B f32 weight
// via register prefetch + convert + swizzled ds_write. C f32.
// ---------------------------------------------------------------------------
__global__ __launch_bounds__(256) void gemm_abf16_bf32(
    const bf16* __restrict__ A, const float* __restrict__ B, float* __restrict__ C,
    int ldc, int K) {
  __shared__ bf16 As[128 * 64];
  __shared__ bf16 Bs[128 * 64];
  const int tid = threadIdx.x;
  const int lane = tid & 63;
  const int wave = tid >> 6;
  const int lrow = lane & 15;
  const int quad = lane >> 4;
  const int wm = (wave >> 1) * 64;
  const int wn = (wave & 1) * 64;
  const int tm = blockIdx.y * 128;
  const int tn = blockIdx.x * 128;

  const int srow = tid >> 3;
  const int scl = tid & 7;
  const int c16 = tid & 15;
  const int br0 = tid >> 4;

  floatx4 acc[4][4] = {};
  float4 breg[8];
#pragma unroll
  for (int r = 0; r < 8; ++r)
    breg[r] = *(const float4*)(B + (size_t)(tn + r * 16 + br0) * K + c16 * 4);

  for (int k0 = 0; k0 < K; k0 += 64) {
    __syncthreads();
#pragma unroll
    for (int r = 0; r < 4; ++r) {
      const int row = r * 32 + srow;
      const int scg = scl ^ (row & 7);
      __builtin_amdgcn_global_load_lds(
          (const __attribute__((address_space(1))) void*)(A + (size_t)(tm + row) * K + k0 + scg * 8),
          (__attribute__((address_space(3))) void*)(As + row * 64 + scl * 8), 16, 0, 0);
    }
#pragma unroll
    for (int r = 0; r < 8; ++r) {
      const int row = r * 16 + br0;
      short4v sv;
      sv[0] = bf16_bits(breg[r].x); sv[1] = bf16_bits(breg[r].y);
      sv[2] = bf16_bits(breg[r].z); sv[3] = bf16_bits(breg[r].w);
      *(short4v*)&Bs[row * 64 + (((c16 >> 1) ^ (row & 7)) * 8) + (c16 & 1) * 4] = sv;
    }
    __syncthreads();
    if (k0 + 64 < K) {
#pragma unroll
      for (int r = 0; r < 8; ++r)
        breg[r] = *(const float4*)(B + (size_t)(tn + r * 16 + br0) * K + k0 + 64 + c16 * 4);
    }

#pragma unroll
    for (int kk = 0; kk < 2; ++kk) {
      short8 af[4], bfr[4];
#pragma unroll
      for (int i = 0; i < 4; ++i) {
        const int ra = wm + i * 16 + lrow;
        const int rb = wn + i * 16 + lrow;
        af[i] = *(const short8*)&As[ra * 64 + (((kk * 4 + quad) ^ (ra & 7)) * 8)];
        bfr[i] = *(const short8*)&Bs[rb * 64 + (((kk * 4 + quad) ^ (rb & 7)) * 8)];
      }
#pragma unroll
      for (int i = 0; i < 4; ++i)
#pragma unroll
        for (int j = 0; j < 4; ++j)
          acc[i][j] = MFMA_BF16(af[i], bfr[j], acc[i][j]);
    }
  }

#pragma unroll
  for (int i = 0; i < 4; ++i)
#pragma unroll
    for (int j = 0; j < 4; ++j)
#pragma unroll
      for (int r = 0; r < 4; ++r) {
        const int row = tm + wm + i * 16 + quad * 4 + r;
        const int col = tn + wn + j * 16 + lrow;
        C[(size_t)row * ldc + col] = acc[i][j][r];
      }
}

// ---------------------------------------------------------------------------
// RoPE, in-place on bf16 qkv. One thread per (b,s,h,q/k,pair). (V untouched.)
// ---------------------------------------------------------------------------
__global__ void rope_kernel(bf16* __restrict__ qkv) {
  const int idx = blockIdx.x * 256 + threadIdx.x;
  const int i = idx & 15;
  int t = idx >> 4;
  const int qk = t & 1;
  t >>= 1;
  const int h = t & 15;
  t >>= 4;
  const int s = t & 2047;
  bf16* p = qkv + (size_t)t * 6144 + (h >> 1) * 768 + (h & 1) * 128 + qk * 256 + 2 * i;
  const float x0 = __bfloat162float(p[0]);
  const float x1 = __bfloat162float(p[1]);
  const float inv = powf(10000.f, -(float)(2 * i) / 32.f);
  const float ang = (float)s * inv;
  float sn, cs;
  sincosf(ang, &sn, &cs);
  p[0] = __float2bfloat16(x0 * cs - x1 * sn);
  p[1] = __float2bfloat16(x1 * cs + x0 * sn);
}

// ---------------------------------------------------------------------------
// Flash attention — occupancy revision (r7).
// r6 counters: MfmaUtil 12, VALUBusy 27, DS ~31%, HBM 17% — nothing
// saturated; 1 block/CU in barrier lockstep = serial-chain latency bound.
// r7: one 128-row q-tile per block, 512 blocks -> 2 co-resident blocks/CU
// (LDS 48KB x2 <= 160KB). Unlike r1's failed attempt this does NOT change
// per-work DS traffic: the paired phases each re-staged K/V from kb=0
// anyway, so the split is traffic-neutral.
// Balanced dispatch pairing: with round-robin XCD dispatch, blocks c and
// c+256 land on the same CU; qb = (i<8) ? 15-i : i-8 (i=bid>>5) makes every
// CU pair sum to exactly 36 k-iters, heavy-first (LPT).
// Also: K-staging XOR chunk swizzle col' = sr ^ (dgrp&7) (write + read) --
// kills the 4-way bank conflict on the K b128 staging writes (2-way = free).
// Internals otherwise identical to the passing r6 kernel.
// ---------------------------------------------------------------------------
__global__ __launch_bounds__(256) void attn_flash_pair(
    const bf16* __restrict__ qkv, const bf16* __restrict__ vT,
    bf16* __restrict__ out) {
  __shared__ short Ks[16 * 64 * 8];  // [dgrp 16][key-chunk 64, swz][8]  16 KB
  __shared__ short Vs[8 * 128 * 8];  // [kgrp 8][d 128][8]               16 KB
  __shared__ short Ps[8 * 128 * 8];  // [kgrp 8][qrow 128][8]            16 KB
  const int tid = threadIdx.x;
  const int wave = tid >> 6;
  const int lane = tid & 63;
  const int lq = lane & 15;   // q index within 16-tile
  const int quad = lane >> 4;

  const int bid = blockIdx.x;
  const int i16 = bid >> 5;
  const int qb = (i16 < 8) ? (15 - i16) : (i16 - 8);  // balanced-pair LPT
  const int h = (bid >> 1) & 15;
  const int b = bid & 1;

  const size_t SROW = 6144;
  const bf16* base = qkv + (size_t)b * 2048 * SROW;
  const int qoff = (h >> 1) * 768 + (h & 1) * 128;
  const int koff = qoff + 256;
  const float scale = 0.088388347648318447f;  // 1/sqrt(128)

  const int sr = tid >> 2;  // K staging row 0..63
  const int sq = tid & 3;   // K staging quarter of the 128-wide d strip
  const bf16* kbase = base + (size_t)sr * SROW + koff + sq * 32;

  // V staging: thread owns d-row (tid>>1), s-half (tid&1)*32; 4 x 16B.
  const bf16* vrow = vT + (size_t)(b * 16 + h) * 262144 +
                     (size_t)(tid >> 1) * 2048 + (tid & 1) * 32;
  short* vdst = &Vs[(((tid & 1) * 4) * 128 + (tid >> 1)) * 8];

  // Prefetch k-block 0 into registers.
  short8 kv[4], vv[4];
#pragma unroll
  for (int j = 0; j < 4; ++j) kv[j] = *(const short8*)(kbase + j * 8);
#pragma unroll
  for (int i = 0; i < 4; ++i) vv[i] = *(const short8*)(vrow + i * 8);

  // Q B-frags: q-col = lane&15, k = quad*8+j.
  short8 qf[2][4];
#pragma unroll
  for (int rt = 0; rt < 2; ++rt) {
    const bf16* qp =
        base + (size_t)(qb * 128 + wave * 32 + rt * 16 + lq) * SROW + qoff + quad * 8;
#pragma unroll
    for (int ks = 0; ks < 4; ++ks) qf[rt][ks] = *(const short8*)(qp + ks * 32);
  }

  floatx4 o[2][8] = {};
  float m_i[2] = {-1e30f, -1e30f};
  float l_i[2] = {0.f, 0.f};

  const int kb_end = 2 * qb + 2;  // causal: only k-blocks overlapping tril
  for (int kb = 0; kb < kb_end; ++kb) {
    __syncthreads();  // all waves done reading Ks/Vs of the previous iter

    // reg -> LDS stage. K: 4 x b128 with XOR chunk swizzle (2-way, free);
    // V: 4 x b128 (vT already d-major), conflict-free.
#pragma unroll
    for (int j = 0; j < 4; ++j) {
      const int dg = sq * 4 + j;
      *(short8*)&Ks[(dg * 64 + (sr ^ (dg & 7))) * 8] = kv[j];
    }
#pragma unroll
    for (int i = 0; i < 4; ++i) *(short8*)(vdst + i * 1024) = vv[i];
    __syncthreads();

    // Issue next tile's global loads; consumed after the next barrier.
    if (kb + 1 < kb_end) {
      const size_t koffg = (size_t)(kb + 1) * 64 * SROW;
      const int voffg = (kb + 1) * 64;
#pragma unroll
      for (int j = 0; j < 4; ++j) kv[j] = *(const short8*)(kbase + koffg + j * 8);
#pragma unroll
      for (int i = 0; i < 4; ++i) vv[i] = *(const short8*)(vrow + voffg + i * 8);
    }

    // S^T = K Q : sc[rt][ct][r] = S[key = kb*64+ct*16+quad*4+r][q = ..+lq]
    floatx4 sc[2][4] = {};
    __builtin_amdgcn_s_setprio(1);
#pragma unroll
    for (int ks = 0; ks < 4; ++ks) {
      const int dg = ks * 4 + quad;
      short8 kf[4];
#pragma unroll
      for (int ct = 0; ct < 4; ++ct)
        kf[ct] = *(const short8*)&Ks[(dg * 64 + ((ct * 16 + lq) ^ (dg & 7))) * 8];
#pragma unroll
      for (int rt = 0; rt < 2; ++rt)
#pragma unroll
        for (int ct = 0; ct < 4; ++ct)
          sc[rt][ct] = MFMA_BF16(kf[ct], qf[rt][ks], sc[rt][ct]);
    }
    __builtin_amdgcn_s_setprio(0);

    // scale + causal mask (diagonal region only) + online softmax per q.
    const int qrow0 = qb * 128 + wave * 32;
    const bool diag = (kb * 64 + 63 > qrow0);  // wave-uniform
#pragma unroll
    for (int rt = 0; rt < 2; ++rt) {
      const int qg = qrow0 + rt * 16 + lq;
#pragma unroll
      for (int ct = 0; ct < 4; ++ct)
#pragma unroll
        for (int r = 0; r < 4; ++r) {
          float v = sc[rt][ct][r] * scale;
          if (diag && (kb * 64 + ct * 16 + quad * 4 + r) > qg) v = -1e9f;
          sc[rt][ct][r] = v;
        }
      // in-lane tree max over the 16 key-values
      float c0 = fmaxf(fmaxf(sc[rt][0][0], sc[rt][0][1]), fmaxf(sc[rt][0][2], sc[rt][0][3]));
      float c1 = fmaxf(fmaxf(sc[rt][1][0], sc[rt][1][1]), fmaxf(sc[rt][1][2], sc[rt][1][3]));
      float c2 = fmaxf(fmaxf(sc[rt][2][0], sc[rt][2][1]), fmaxf(sc[rt][2][2], sc[rt][2][3]));
      float c3 = fmaxf(fmaxf(sc[rt][3][0], sc[rt][3][1]), fmaxf(sc[rt][3][2], sc[rt][3][3]));
      float mx = fmaxf(fmaxf(c0, c1), fmaxf(c2, c3));
      // cross-quad (lanes lq, lq+16, lq+32, lq+48 hold disjoint keys)
      mx = fmaxf(mx, __shfl_xor(mx, 16, 64));
      mx = fmaxf(mx, __shfl_xor(mx, 32, 64));
      float mnew = m_i[rt];
      if (!__all(mx <= mnew)) {  // exact skip: alpha==1 when max unchanged
        mnew = fmaxf(mnew, mx);
        const float alpha = __expf(m_i[rt] - mnew);
        m_i[rt] = mnew;
        l_i[rt] *= alpha;
#pragma unroll
        for (int dt = 0; dt < 8; ++dt) o[rt][dt] *= alpha;
      }
      float s0 = 0.f, s1 = 0.f, s2 = 0.f, s3 = 0.f;
#pragma unroll
      for (int ct = 0; ct < 4; ++ct) {
        const float p0 = __expf(sc[rt][ct][0] - mnew);
        const float p1 = __expf(sc[rt][ct][1] - mnew);
        const float p2 = __expf(sc[rt][ct][2] - mnew);
        const float p3 = __expf(sc[rt][ct][3] - mnew);
        sc[rt][ct][0] = p0; sc[rt][ct][1] = p1; sc[rt][ct][2] = p2; sc[rt][ct][3] = p3;
        s0 += p0; s1 += p1; s2 += p2; s3 += p3;
      }
      float rs = (s0 + s1) + (s2 + s3);
      rs += __shfl_xor(rs, 16, 64);
      rs += __shfl_xor(rs, 32, 64);
      l_i[rt] += rs;
      // P pack + b64 store: keys ct*16 + quad*4 + (0..3) of q-row `prow`.
      const int prow = wave * 32 + rt * 16 + lq;
#pragma unroll
      for (int ct = 0; ct < 4; ++ct) {
        short4v pv;
        pv[0] = bf16_bits(sc[rt][ct][0]); pv[1] = bf16_bits(sc[rt][ct][1]);
        pv[2] = bf16_bits(sc[rt][ct][2]); pv[3] = bf16_bits(sc[rt][ct][3]);
        const int kgrp = ct * 2 + (quad >> 1);
        *(short4v*)&Ps[(kgrp * 128 + prow) * 8 + (quad & 1) * 4] = pv;
      }
    }

    // O^T += V P : o[rt][dt] rows = d (quad*4+r), cols = q (lane&15).
    // Same-wave LDS RAW on Ps (each wave reads only its own 32 q-rows).
    __builtin_amdgcn_s_setprio(1);
#pragma unroll
    for (int kk = 0; kk < 2; ++kk) {
      short8 pf[2], vf[8];
#pragma unroll
      for (int rt = 0; rt < 2; ++rt)
        pf[rt] = *(const short8*)&Ps[((kk * 4 + quad) * 128 + wave * 32 + rt * 16 + lq) * 8];
#pragma unroll
      for (int dt = 0; dt < 8; ++dt)
        vf[dt] = *(const short8*)&Vs[((kk * 4 + quad) * 128 + dt * 16 + lq) * 8];
#pragma unroll
      for (int rt = 0; rt < 2; ++rt)
#pragma unroll
        for (int dt = 0; dt < 8; ++dt)
          o[rt][dt] = MFMA_BF16(vf[dt], pf[rt], o[rt][dt]);
    }
    __builtin_amdgcn_s_setprio(0);
  }

  // epilogue: out[q][d] = O^T[d][q] / l. Packed 4-wide bf16 stores.
#pragma unroll
  for (int rt = 0; rt < 2; ++rt) {
    const float inv_l = 1.f / l_i[rt];
    const int qg = qb * 128 + wave * 32 + rt * 16 + lq;
    bf16* op = out + ((size_t)(b * 2048 + qg)) * 2048 + h * 128 + quad * 4;
#pragma unroll
    for (int dt = 0; dt < 8; ++dt) {
      short4v s4;
      s4[0] = bf16_bits(o[rt][dt][0] * inv_l);
      s4[1] = bf16_bits(o[rt][dt][1] * inv_l);
      s4[2] = bf16_bits(o[rt][dt][2] * inv_l);
      s4[3] = bf16_bits(o[rt][dt][3] * inv_l);
      *(short4v*)(op + dt * 16) = s4;
    }
  }
}

// ---------------------------------------------------------------------------
// Workspace budget:
//   d_ws:  [0, 48 MiB)  qkv (v-slots unused); [48, 64 MiB) flex: W_qkv half,
//          then attnout
//   d_out: [0, 16 MiB)  hidden_bf16 scratch (dead before GEMM2 rewrites)
//          [16, 32 MiB) vT (b,h,d,s) bf16 — written by GEMM1, read by attn,
//          dead before GEMM2 writes outp.
// ---------------------------------------------------------------------------
extern "C" void kernel_launch(void* const* d_in, const int* in_sizes, int n_in,
                              void* d_out, int out_size, void* d_ws, size_t ws_size,
                              hipStream_t stream) {
  const float* hidden = (const float*)d_in[0];  // (2,2048,2048) f32
  const float* Wqkv = (const float*)d_in[1];    // (6144,2048)  f32
  const float* Wout = (const float*)d_in[2];    // (2048,2048)  f32
  float* outp = (float*)d_out;                  // (2,2048,2048) f32

  bf16* qkv = (bf16*)d_ws;                    // 48 MiB
  bf16* flex = qkv + (size_t)4096 * 6144;     // 16 MiB flex
  bf16* hbf = (bf16*)d_out;                   // d_out scratch, 16 MiB
  bf16* vT = (bf16*)d_out + (size_t)8 * 1024 * 1024;  // d_out[16,32 MiB)

  f32_to_bf16_kernel<<<4096, 256, 0, stream>>>(hidden, hbf, 1048576);

  f32_to_bf16_kernel<<<3072, 256, 0, stream>>>(Wqkv, flex, 786432);
  gemm_bt_async<bf16><<<dim3(24, 32), 256, 0, stream>>>(hbf, flex, qkv, 6144, 2048, vT, 0);
  f32_to_bf16_kernel<<<3072, 256, 0, stream>>>(Wqkv + (size_t)3072 * 2048, flex, 786432);
  gemm_bt_async<bf16><<<dim3(24, 32), 256, 0, stream>>>(hbf, flex, qkv + 3072, 6144, 2048, vT, 8);

  rope_kernel<<<8192, 256, 0, stream>>>(qkv);

  bf16* attnout = flex;
  attn_flash_pair<<<512, 256, 0, stream>>>(qkv, vT, attnout);

  gemm_abf16_bf32<<<dim3(16, 32), 256, 0, stream>>>(attnout, Wout, outp, 2048, 2048);
}

// Round 8
// 432.822 us; speedup vs baseline: 1.0087x; 1.0087x over previous
//
#include <hip/hip_runtime.h>
#include <hip/hip_bf16.h>
#include <cstdint>
#include <cstddef>

using bf16 = __hip_bfloat16;
using short4v = __attribute__((ext_vector_type(4))) short;  // 4 bf16 (2 VGPRs)
using short8 = __attribute__((ext_vector_type(8))) short;   // 8 bf16 (4 VGPRs)
using floatx4 = __attribute__((ext_vector_type(4))) float;  // MFMA C/D frag

#define MFMA_BF16(A, B, C) __builtin_amdgcn_mfma_f32_16x16x32_bf16((A), (B), (C), 0, 0, 0)

__device__ inline short bf16_bits(float x) {
  bf16 v = __float2bfloat16(x);
  short r;
  __builtin_memcpy(&r, &v, 2);
  return r;
}

__device__ inline void store_c(bf16* p, float v) { *p = __float2bfloat16(v); }
__device__ inline void store_c(float* p, float v) { *p = v; }

// ---------------------------------------------------------------------------
// f32 -> bf16 bulk convert (RNE). 8 elements/thread, 16B stores.
// ---------------------------------------------------------------------------
__global__ __launch_bounds__(256) void f32_to_bf16_kernel(
    const float* __restrict__ src, bf16* __restrict__ dst, int n8) {
  const int i = blockIdx.x * 256 + threadIdx.x;
  if (i >= n8) return;
  const float4 a = ((const float4*)src)[2 * i];
  const float4 b = ((const float4*)src)[2 * i + 1];
  short8 r;
  r[0] = bf16_bits(a.x); r[1] = bf16_bits(a.y); r[2] = bf16_bits(a.z); r[3] = bf16_bits(a.w);
  r[4] = bf16_bits(b.x); r[5] = bf16_bits(b.y); r[6] = bf16_bits(b.z); r[7] = bf16_bits(b.w);
  *(short8*)(dst + (size_t)i * 8) = r;
}

// ---------------------------------------------------------------------------
// GEMM (m97 structure): C[m,n] = sum_k A[m,k]*B[n,k], A,B row-major bf16,
// row stride K; C row-major stride ldc. Tile 128x128, BK=64, 4 waves (2x2).
// global_load_lds width=16 staging with XOR chunk swizzle.
// vT redirect (r6, proven): v-region column tiles (tn%6 >= 4) store
// pre-TRANSPOSED V into vT[b][h][d][s] as packed 8B stores.
// ---------------------------------------------------------------------------
template <typename TC>
__global__ __launch_bounds__(256) void gemm_bt_async(
    const bf16* __restrict__ A, const bf16* __restrict__ B, TC* __restrict__ C,
    int ldc, int K, bf16* __restrict__ vT, int mpbase) {
  __shared__ bf16 As[128 * 64];
  __shared__ bf16 Bs[128 * 64];
  const int tid = threadIdx.x;
  const int lane = tid & 63;
  const int wave = tid >> 6;
  const int lrow = lane & 15;
  const int quad = lane >> 4;
  const int wm = (wave >> 1) * 64;
  const int wn = (wave & 1) * 64;
  const int tm = blockIdx.y * 128;
  const int tn = blockIdx.x * 128;

  const int srow = tid >> 3;
  const int scl = tid & 7;

  floatx4 acc[4][4] = {};

  for (int k0 = 0; k0 < K; k0 += 64) {
    __syncthreads();
#pragma unroll
    for (int r = 0; r < 4; ++r) {
      const int row = r * 32 + srow;
      const int scg = scl ^ (row & 7);
      __builtin_amdgcn_global_load_lds(
          (const __attribute__((address_space(1))) void*)(A + (size_t)(tm + row) * K + k0 + scg * 8),
          (__attribute__((address_space(3))) void*)(As + row * 64 + scl * 8), 16, 0, 0);
    }
#pragma unroll
    for (int r = 0; r < 4; ++r) {
      const int row = r * 32 + srow;
      const int scg = scl ^ (row & 7);
      __builtin_amdgcn_global_load_lds(
          (const __attribute__((address_space(1))) void*)(B + (size_t)(tn + row) * K + k0 + scg * 8),
          (__attribute__((address_space(3))) void*)(Bs + row * 64 + scl * 8), 16, 0, 0);
    }
    __syncthreads();

#pragma unroll
    for (int kk = 0; kk < 2; ++kk) {
      short8 af[4], bfr[4];
#pragma unroll
      for (int i = 0; i < 4; ++i) {
        const int ra = wm + i * 16 + lrow;
        const int rb = wn + i * 16 + lrow;
        af[i] = *(const short8*)&As[ra * 64 + (((kk * 4 + quad) ^ (ra & 7)) * 8)];
        bfr[i] = *(const short8*)&Bs[rb * 64 + (((kk * 4 + quad) ^ (rb & 7)) * 8)];
      }
#pragma unroll
      for (int i = 0; i < 4; ++i)
#pragma unroll
        for (int j = 0; j < 4; ++j)
          acc[i][j] = MFMA_BF16(af[i], bfr[j], acc[i][j]);
    }
  }

  if (vT != nullptr && ((int)blockIdx.x % 6) >= 4) {
    // v-region tile: store transposed into vT[((b*16+h)*128+d)*2048 + s].
    const int mpl = (int)blockIdx.x / 6;
#pragma unroll
    for (int i = 0; i < 4; ++i)
#pragma unroll
      for (int j = 0; j < 4; ++j) {
        const int fl = tn + wn + j * 16 + lrow;   // col within this call's 3072
        const int sv = fl - mpl * 768 - 512;      // 0..255
        const int hh = mpbase + mpl * 2 + (sv >> 7);
        const int dd = sv & 127;
        const int m0 = tm + wm + i * 16 + quad * 4;  // 4 consecutive s rows
        const int bb = m0 >> 11;
        const int ss = m0 & 2047;
        short4v pv;
        pv[0] = bf16_bits(acc[i][j][0]); pv[1] = bf16_bits(acc[i][j][1]);
        pv[2] = bf16_bits(acc[i][j][2]); pv[3] = bf16_bits(acc[i][j][3]);
        *(short4v*)&vT[((size_t)(bb * 16 + hh) * 128 + dd) * 2048 + ss] = pv;
      }
  } else {
#pragma unroll
    for (int i = 0; i < 4; ++i)
#pragma unroll
      for (int j = 0; j < 4; ++j)
#pragma unroll
        for (int r = 0; r < 4; ++r) {
          const int row = tm + wm + i * 16 + quad * 4 + r;
          const int col = tn + wn + j * 16 + lrow;
          store_c(&C[(size_t)row * ldc + col], acc[i][j][r]);
        }
  }
}

// ---------------------------------------------------------------------------
// Mixed GEMM for the out-projection: A bf16 via global_load_lds; B f32 weight
// via register prefetch + convert + swizzled ds_write. C f32.
// ---------------------------------------------------------------------------
__global__ __launch_bounds__(256) void gemm_abf16_bf32(
    const bf16* __restrict__ A, const float* __restrict__ B, float* __restrict__ C,
    int ldc, int K) {
  __shared__ bf16 As[128 * 64];
  __shared__ bf16 Bs[128 * 64];
  const int tid = threadIdx.x;
  const int lane = tid & 63;
  const int wave = tid >> 6;
  const int lrow = lane & 15;
  const int quad = lane >> 4;
  const int wm = (wave >> 1) * 64;
  const int wn = (wave & 1) * 64;
  const int tm = blockIdx.y * 128;
  const int tn = blockIdx.x * 128;

  const int srow = tid >> 3;
  const int scl = tid & 7;
  const int c16 = tid & 15;
  const int br0 = tid >> 4;

  floatx4 acc[4][4] = {};
  float4 breg[8];
#pragma unroll
  for (int r = 0; r < 8; ++r)
    breg[r] = *(const float4*)(B + (size_t)(tn + r * 16 + br0) * K + c16 * 4);

  for (int k0 = 0; k0 < K; k0 += 64) {
    __syncthreads();
#pragma unroll
    for (int r = 0; r < 4; ++r) {
      const int row = r * 32 + srow;
      const int scg = scl ^ (row & 7);
      __builtin_amdgcn_global_load_lds(
          (const __attribute__((address_space(1))) void*)(A + (size_t)(tm + row) * K + k0 + scg * 8),
          (__attribute__((address_space(3))) void*)(As + row * 64 + scl * 8), 16, 0, 0);
    }
#pragma unroll
    for (int r = 0; r < 8; ++r) {
      const int row = r * 16 + br0;
      short4v sv;
      sv[0] = bf16_bits(breg[r].x); sv[1] = bf16_bits(breg[r].y);
      sv[2] = bf16_bits(breg[r].z); sv[3] = bf16_bits(breg[r].w);
      *(short4v*)&Bs[row * 64 + (((c16 >> 1) ^ (row & 7)) * 8) + (c16 & 1) * 4] = sv;
    }
    __syncthreads();
    if (k0 + 64 < K) {
#pragma unroll
      for (int r = 0; r < 8; ++r)
        breg[r] = *(const float4*)(B + (size_t)(tn + r * 16 + br0) * K + k0 + 64 + c16 * 4);
    }

#pragma unroll
    for (int kk = 0; kk < 2; ++kk) {
      short8 af[4], bfr[4];
#pragma unroll
      for (int i = 0; i < 4; ++i) {
        const int ra = wm + i * 16 + lrow;
        const int rb = wn + i * 16 + lrow;
        af[i] = *(const short8*)&As[ra * 64 + (((kk * 4 + quad) ^ (ra & 7)) * 8)];
        bfr[i] = *(const short8*)&Bs[rb * 64 + (((kk * 4 + quad) ^ (rb & 7)) * 8)];
      }
#pragma unroll
      for (int i = 0; i < 4; ++i)
#pragma unroll
        for (int j = 0; j < 4; ++j)
          acc[i][j] = MFMA_BF16(af[i], bfr[j], acc[i][j]);
    }
  }

#pragma unroll
  for (int i = 0; i < 4; ++i)
#pragma unroll
    for (int j = 0; j < 4; ++j)
#pragma unroll
      for (int r = 0; r < 4; ++r) {
        const int row = tm + wm + i * 16 + quad * 4 + r;
        const int col = tn + wn + j * 16 + lrow;
        C[(size_t)row * ldc + col] = acc[i][j][r];
      }
}

// ---------------------------------------------------------------------------
// RoPE, in-place on bf16 qkv. One thread per (b,s,h,q/k,pair). (V untouched.)
// ---------------------------------------------------------------------------
__global__ void rope_kernel(bf16* __restrict__ qkv) {
  const int idx = blockIdx.x * 256 + threadIdx.x;
  const int i = idx & 15;
  int t = idx >> 4;
  const int qk = t & 1;
  t >>= 1;
  const int h = t & 15;
  t >>= 4;
  const int s = t & 2047;
  bf16* p = qkv + (size_t)t * 6144 + (h >> 1) * 768 + (h & 1) * 128 + qk * 256 + 2 * i;
  const float x0 = __bfloat162float(p[0]);
  const float x1 = __bfloat162float(p[1]);
  const float inv = powf(10000.f, -(float)(2 * i) / 32.f);
  const float ang = (float)s * inv;
  float sn, cs;
  sincosf(ang, &sn, &cs);
  p[0] = __float2bfloat16(x0 * cs - x1 * sn);
  p[1] = __float2bfloat16(x1 * cs + x0 * sn);
}

// ---------------------------------------------------------------------------
// Flash attention — BK=128 revision (r8).
// r7 falsified occupancy pairing (light partner finishes in 6% of makespan);
// counters say per-iteration overhead + serial chain is the cost: 2 barrier
// drains + 8 shuffle-latency chains + rescale/merge per 64 keys. r8 halves
// all per-iter overheads by processing 128 keys per iteration:
//   * LDS: Ks[16dg][128key][8] 32KB + Vs[16kg][128d][8] 32KB +
//     Ps[16kg][128row][8] 32KB = 96KB (1 block/CU — matches observed regime).
//   * Staging via global_load_lds (16B): per-lane GLOBAL addresses with
//     linear LDS dest (m173 pattern). No staging ds_writes, no prefetch
//     registers, HW-contiguous LDS writes (conflict-free). Latency exposed
//     at the stage barrier (~600cy/iter) — trade accepted vs T14.
//   * Softmax: scale folded into exp args (exp((s-m)*scale), bit-equal);
//     l-sum SHUFFLES DEFERRED to epilogue (per-quad partial l, alpha is
//     row-global so partials scale consistently); 2 max-shuffles per rt per
//     128 keys (was 8 shuffle chains per 128 keys).
//   * Exact skip-rescale via __all (r6-proven).
// Grid (8,16,2); phases qb = bx then 15-bx -> uniform 17 iters per block.
// ---------------------------------------------------------------------------
__global__ __launch_bounds__(256) void attn_flash_pair(
    const bf16* __restrict__ qkv, const bf16* __restrict__ vT,
    bf16* __restrict__ out) {
  __shared__ short Ks[16 * 128 * 8];  // [dgrp 16][key 128][8]   32 KB
  __shared__ short Vs[16 * 128 * 8];  // [kgrp 16][d 128][8]     32 KB
  __shared__ short Ps[16 * 128 * 8];  // [kgrp 16][qrow 128][8]  32 KB
  const int tid = threadIdx.x;
  const int wave = tid >> 6;
  const int lane = tid & 63;
  const int lq = lane & 15;   // q index within 16-tile
  const int quad = lane >> 4;
  const int h = blockIdx.y;
  const int b = blockIdx.z;
  const size_t SROW = 6144;
  const bf16* base = qkv + (size_t)b * 2048 * SROW;
  const bf16* vbase = vT + (size_t)(b * 16 + h) * 262144;
  const int qoff = (h >> 1) * 768 + (h & 1) * 128;
  const int koff = qoff + 256;
  const float scale = 0.088388347648318447f;  // 1/sqrt(128)

  for (int phase = 0; phase < 2; ++phase) {
    const int qb = phase ? (15 - (int)blockIdx.x) : (int)blockIdx.x;

    // Q B-frags: q-col = lane&15, k = quad*8+j (r5-proven load).
    short8 qf[2][4];
#pragma unroll
    for (int rt = 0; rt < 2; ++rt) {
      const bf16* qp =
          base + (size_t)(qb * 128 + wave * 32 + rt * 16 + lq) * SROW + qoff + quad * 8;
#pragma unroll
      for (int ks = 0; ks < 4; ++ks) qf[rt][ks] = *(const short8*)(qp + ks * 32);
    }

    floatx4 o[2][8] = {};
    float m_i[2] = {-1e30f, -1e30f};
    float l_acc[2] = {0.f, 0.f};

    const int kb_end = qb + 1;  // 128-key blocks overlapping tril
    for (int kb = 0; kb < kb_end; ++kb) {
      __syncthreads();  // all waves done reading Ks/Vs/Ps of previous iter

      // Stage K and V tiles via global_load_lds: 8+8 instrs per wave.
      // Unit u = wave*8+i: g = u>>1 (dgrp / kgrp), half = (u&1)*64.
      // K chunk (g, key): 16B = K[key][g*8..+8); lane l -> key = half+l.
      // V chunk (g, d):   16B = V[g*8..+8)[d];   lane l -> d   = half+l.
#pragma unroll
      for (int i = 0; i < 8; ++i) {
        const int u = wave * 8 + i;
        const int g = u >> 1;
        const int half = (u & 1) * 64;
        __builtin_amdgcn_global_load_lds(
            (const __attribute__((address_space(1))) void*)(
                base + (size_t)(kb * 128 + half + lane) * SROW + koff + g * 8),
            (__attribute__((address_space(3))) void*)(Ks + (g * 128 + half + lane) * 8),
            16, 0, 0);
        __builtin_amdgcn_global_load_lds(
            (const __attribute__((address_space(1))) void*)(
                vbase + (size_t)(half + lane) * 2048 + kb * 128 + g * 8),
            (__attribute__((address_space(3))) void*)(Vs + (g * 128 + half + lane) * 8),
            16, 0, 0);
      }
      __syncthreads();  // compiler drains vmcnt before the barrier (m97 pattern)

      // S^T = K Q : sc[rt][ct][r] = S_raw[key = kb*128+ct*16+quad*4+r][q]
      floatx4 sc[2][8] = {};
      __builtin_amdgcn_s_setprio(1);
#pragma unroll
      for (int ks = 0; ks < 4; ++ks) {
        const int dg = ks * 4 + quad;
        short8 kf[8];
#pragma unroll
        for (int ct = 0; ct < 8; ++ct)
          kf[ct] = *(const short8*)&Ks[(dg * 128 + ct * 16 + lq) * 8];
#pragma unroll
        for (int rt = 0; rt < 2; ++rt)
#pragma unroll
          for (int ct = 0; ct < 8; ++ct)
            sc[rt][ct] = MFMA_BF16(kf[ct], qf[rt][ks], sc[rt][ct]);
      }
      __builtin_amdgcn_s_setprio(0);

      // causal mask (diag iter only) + online softmax per q (raw domain,
      // scale folded into exp args; l shuffles deferred to epilogue).
      const int qrow0 = qb * 128 + wave * 32;
      const bool diag = (kb == qb);  // block-uniform
#pragma unroll
      for (int rt = 0; rt < 2; ++rt) {
        const int qg = qrow0 + rt * 16 + lq;
        if (diag) {
#pragma unroll
          for (int ct = 0; ct < 8; ++ct)
#pragma unroll
            for (int r = 0; r < 4; ++r)
              if (kb * 128 + ct * 16 + quad * 4 + r > qg) sc[rt][ct][r] = -1e9f;
        }
        float cm[8];
#pragma unroll
        for (int ct = 0; ct < 8; ++ct)
          cm[ct] = fmaxf(fmaxf(sc[rt][ct][0], sc[rt][ct][1]),
                         fmaxf(sc[rt][ct][2], sc[rt][ct][3]));
        float mx = fmaxf(fmaxf(fmaxf(cm[0], cm[1]), fmaxf(cm[2], cm[3])),
                         fmaxf(fmaxf(cm[4], cm[5]), fmaxf(cm[6], cm[7])));
        mx = fmaxf(mx, __shfl_xor(mx, 16, 64));
        mx = fmaxf(mx, __shfl_xor(mx, 32, 64));
        float mcur = m_i[rt];
        if (!__all(mx <= mcur)) {  // exact skip: alpha==1 when max unchanged
          const float mnew = fmaxf(mcur, mx);
          const float alpha = __expf((mcur - mnew) * scale);
          m_i[rt] = mnew;
          mcur = mnew;
          l_acc[rt] *= alpha;
#pragma unroll
          for (int dt = 0; dt < 8; ++dt) o[rt][dt] *= alpha;
        }
        float s0 = 0.f, s1 = 0.f, s2 = 0.f, s3 = 0.f;
#pragma unroll
        for (int ct = 0; ct < 8; ++ct) {
          const float p0 = __expf((sc[rt][ct][0] - mcur) * scale);
          const float p1 = __expf((sc[rt][ct][1] - mcur) * scale);
          const float p2 = __expf((sc[rt][ct][2] - mcur) * scale);
          const float p3 = __expf((sc[rt][ct][3] - mcur) * scale);
          sc[rt][ct][0] = p0; sc[rt][ct][1] = p1; sc[rt][ct][2] = p2; sc[rt][ct][3] = p3;
          s0 += p0; s1 += p1; s2 += p2; s3 += p3;
        }
        l_acc[rt] += (s0 + s1) + (s2 + s3);  // per-quad partial; reduced at end
        // P pack + b64 store: keys ct*16 + quad*4 + (0..3) of q-row `prow`.
        const int prow = wave * 32 + rt * 16 + lq;
#pragma unroll
        for (int ct = 0; ct < 8; ++ct) {
          short4v pv;
          pv[0] = bf16_bits(sc[rt][ct][0]); pv[1] = bf16_bits(sc[rt][ct][1]);
          pv[2] = bf16_bits(sc[rt][ct][2]); pv[3] = bf16_bits(sc[rt][ct][3]);
          const int kgrp = ct * 2 + (quad >> 1);
          *(short4v*)&Ps[(kgrp * 128 + prow) * 8 + (quad & 1) * 4] = pv;
        }
      }

      // O^T += V P : o[rt][dt] rows = d (quad*4+r), cols = q (lane&15).
      // Same-wave LDS RAW on Ps (each wave reads only its own 32 q-rows).
      __builtin_amdgcn_s_setprio(1);
#pragma unroll
      for (int kk = 0; kk < 4; ++kk) {
        short8 pf[2], vf[8];
#pragma unroll
        for (int rt = 0; rt < 2; ++rt)
          pf[rt] = *(const short8*)&Ps[((kk * 4 + quad) * 128 + wave * 32 + rt * 16 + lq) * 8];
#pragma unroll
        for (int dt = 0; dt < 8; ++dt)
          vf[dt] = *(const short8*)&Vs[((kk * 4 + quad) * 128 + dt * 16 + lq) * 8];
#pragma unroll
        for (int rt = 0; rt < 2; ++rt)
#pragma unroll
          for (int dt = 0; dt < 8; ++dt)
            o[rt][dt] = MFMA_BF16(vf[dt], pf[rt], o[rt][dt]);
      }
      __builtin_amdgcn_s_setprio(0);
    }

    // epilogue: reduce per-quad l partials (deferred shuffles), store O^T/l.
#pragma unroll
    for (int rt = 0; rt < 2; ++rt) {
      float l = l_acc[rt];
      l += __shfl_xor(l, 16, 64);
      l += __shfl_xor(l, 32, 64);
      const float inv_l = 1.f / l;
      const int qg = qb * 128 + wave * 32 + rt * 16 + lq;
      bf16* op = out + ((size_t)(b * 2048 + qg)) * 2048 + h * 128 + quad * 4;
#pragma unroll
      for (int dt = 0; dt < 8; ++dt) {
        short4v s4;
        s4[0] = bf16_bits(o[rt][dt][0] * inv_l);
        s4[1] = bf16_bits(o[rt][dt][1] * inv_l);
        s4[2] = bf16_bits(o[rt][dt][2] * inv_l);
        s4[3] = bf16_bits(o[rt][dt][3] * inv_l);
        *(short4v*)(op + dt * 16) = s4;
      }
    }
  }
}

// ---------------------------------------------------------------------------
// Workspace budget:
//   d_ws:  [0, 48 MiB)  qkv (v-slots unused); [48, 64 MiB) flex: W_qkv half,
//          then attnout
//   d_out: [0, 16 MiB)  hidden_bf16 scratch (dead before GEMM2 rewrites)
//          [16, 32 MiB) vT (b,h,d,s) bf16 — written by GEMM1, read by attn,
//          dead before GEMM2 writes outp.
// ---------------------------------------------------------------------------
extern "C" void kernel_launch(void* const* d_in, const int* in_sizes, int n_in,
                              void* d_out, int out_size, void* d_ws, size_t ws_size,
                              hipStream_t stream) {
  const float* hidden = (const float*)d_in[0];  // (2,2048,2048) f32
  const float* Wqkv = (const float*)d_in[1];    // (6144,2048)  f32
  const float* Wout = (const float*)d_in[2];    // (2048,2048)  f32
  float* outp = (float*)d_out;                  // (2,2048,2048) f32

  bf16* qkv = (bf16*)d_ws;                    // 48 MiB
  bf16* flex = qkv + (size_t)4096 * 6144;     // 16 MiB flex
  bf16* hbf = (bf16*)d_out;                   // d_out scratch, 16 MiB
  bf16* vT = (bf16*)d_out + (size_t)8 * 1024 * 1024;  // d_out[16,32 MiB)

  f32_to_bf16_kernel<<<4096, 256, 0, stream>>>(hidden, hbf, 1048576);

  f32_to_bf16_kernel<<<3072, 256, 0, stream>>>(Wqkv, flex, 786432);
  gemm_bt_async<bf16><<<dim3(24, 32), 256, 0, stream>>>(hbf, flex, qkv, 6144, 2048, vT, 0);
  f32_to_bf16_kernel<<<3072, 256, 0, stream>>>(Wqkv + (size_t)3072 * 2048, flex, 786432);
  gemm_bt_async<bf16><<<dim3(24, 32), 256, 0, stream>>>(hbf, flex, qkv + 3072, 6144, 2048, vT, 8);

  rope_kernel<<<8192, 256, 0, stream>>>(qkv);

  bf16* attnout = flex;
  attn_flash_pair<<<dim3(8, 16, 2), 256, 0, stream>>>(qkv, vT, attnout);

  gemm_abf16_bf32<<<dim3(16, 32), 256, 0, stream>>>(attnout, Wout, outp, 2048, 2048);
}

// Round 9
// 421.958 us; speedup vs baseline: 1.0347x; 1.0257x over previous
//
#include <hip/hip_runtime.h>
#include <hip/hip_bf16.h>
#include <cstdint>
#include <cstddef>

using bf16 = __hip_bfloat16;
using short4v = __attribute__((ext_vector_type(4))) short;  // 4 bf16 (2 VGPRs)
using short8 = __attribute__((ext_vector_type(8))) short;   // 8 bf16 (4 VGPRs)
using floatx4 = __attribute__((ext_vector_type(4))) float;  // MFMA C/D frag

#define MFMA_BF16(A, B, C) __builtin_amdgcn_mfma_f32_16x16x32_bf16((A), (B), (C), 0, 0, 0)

__device__ inline short bf16_bits(float x) {
  bf16 v = __float2bfloat16(x);
  short r;
  __builtin_memcpy(&r, &v, 2);
  return r;
}

__device__ inline void store_c(bf16* p, float v) { *p = __float2bfloat16(v); }
__device__ inline void store_c(float* p, float v) { *p = v; }

// ---------------------------------------------------------------------------
// f32 -> bf16 bulk convert (RNE). 8 elements/thread, 16B stores.
// ---------------------------------------------------------------------------
__global__ __launch_bounds__(256) void f32_to_bf16_kernel(
    const float* __restrict__ src, bf16* __restrict__ dst, int n8) {
  const int i = blockIdx.x * 256 + threadIdx.x;
  if (i >= n8) return;
  const float4 a = ((const float4*)src)[2 * i];
  const float4 b = ((const float4*)src)[2 * i + 1];
  short8 r;
  r[0] = bf16_bits(a.x); r[1] = bf16_bits(a.y); r[2] = bf16_bits(a.z); r[3] = bf16_bits(a.w);
  r[4] = bf16_bits(b.x); r[5] = bf16_bits(b.y); r[6] = bf16_bits(b.z); r[7] = bf16_bits(b.w);
  *(short8*)(dst + (size_t)i * 8) = r;
}

// ---------------------------------------------------------------------------
// GEMM (m97 structure): C[m,n] = sum_k A[m,k]*B[n,k], A,B row-major bf16,
// row stride K; C row-major stride ldc. Tile 128x128, BK=64, 4 waves (2x2).
// global_load_lds width=16 staging with XOR chunk swizzle.
// r9: XCD-aware block swizzle (T1) — linear bid % 8 = XCD (round-robin
// dispatch, m09); giving each XCD a contiguous swz range makes its blocks
// share a ~2MB A-panel in its private 4MB L2. Requires nwg % 8 == 0
// (768 and 512 both qualify; bijective).
// vT redirect (r6, proven): v-region column tiles (bxs%6 >= 4) store
// pre-TRANSPOSED V into vT[b][h][d][s] as packed 8B stores.
// ---------------------------------------------------------------------------
template <typename TC>
__global__ __launch_bounds__(256) void gemm_bt_async(
    const bf16* __restrict__ A, const bf16* __restrict__ B, TC* __restrict__ C,
    int ldc, int K, bf16* __restrict__ vT, int mpbase) {
  __shared__ bf16 As[128 * 64];
  __shared__ bf16 Bs[128 * 64];
  const int tid = threadIdx.x;
  const int lane = tid & 63;
  const int wave = tid >> 6;
  const int lrow = lane & 15;
  const int quad = lane >> 4;
  const int wm = (wave >> 1) * 64;
  const int wn = (wave & 1) * 64;

  // T1 XCD swizzle (bijective when nwg % 8 == 0).
  const int nbx = gridDim.x;
  const int lin = blockIdx.y * nbx + blockIdx.x;
  const int cpx = (nbx * gridDim.y) >> 3;
  const int swz = (lin & 7) * cpx + (lin >> 3);
  const int bxs = swz % nbx;
  const int bys = swz / nbx;
  const int tm = bys * 128;
  const int tn = bxs * 128;

  const int srow = tid >> 3;
  const int scl = tid & 7;

  floatx4 acc[4][4] = {};

  for (int k0 = 0; k0 < K; k0 += 64) {
    __syncthreads();
#pragma unroll
    for (int r = 0; r < 4; ++r) {
      const int row = r * 32 + srow;
      const int scg = scl ^ (row & 7);
      __builtin_amdgcn_global_load_lds(
          (const __attribute__((address_space(1))) void*)(A + (size_t)(tm + row) * K + k0 + scg * 8),
          (__attribute__((address_space(3))) void*)(As + row * 64 + scl * 8), 16, 0, 0);
    }
#pragma unroll
    for (int r = 0; r < 4; ++r) {
      const int row = r * 32 + srow;
      const int scg = scl ^ (row & 7);
      __builtin_amdgcn_global_load_lds(
          (const __attribute__((address_space(1))) void*)(B + (size_t)(tn + row) * K + k0 + scg * 8),
          (__attribute__((address_space(3))) void*)(Bs + row * 64 + scl * 8), 16, 0, 0);
    }
    __syncthreads();

#pragma unroll
    for (int kk = 0; kk < 2; ++kk) {
      short8 af[4], bfr[4];
#pragma unroll
      for (int i = 0; i < 4; ++i) {
        const int ra = wm + i * 16 + lrow;
        const int rb = wn + i * 16 + lrow;
        af[i] = *(const short8*)&As[ra * 64 + (((kk * 4 + quad) ^ (ra & 7)) * 8)];
        bfr[i] = *(const short8*)&Bs[rb * 64 + (((kk * 4 + quad) ^ (rb & 7)) * 8)];
      }
#pragma unroll
      for (int i = 0; i < 4; ++i)
#pragma unroll
        for (int j = 0; j < 4; ++j)
          acc[i][j] = MFMA_BF16(af[i], bfr[j], acc[i][j]);
    }
  }

  if (vT != nullptr && (bxs % 6) >= 4) {
    // v-region tile: store transposed into vT[((b*16+h)*128+d)*2048 + s].
    const int mpl = bxs / 6;
#pragma unroll
    for (int i = 0; i < 4; ++i)
#pragma unroll
      for (int j = 0; j < 4; ++j) {
        const int fl = tn + wn + j * 16 + lrow;   // col within this call's 3072
        const int sv = fl - mpl * 768 - 512;      // 0..255
        const int hh = mpbase + mpl * 2 + (sv >> 7);
        const int dd = sv & 127;
        const int m0 = tm + wm + i * 16 + quad * 4;  // 4 consecutive s rows
        const int bb = m0 >> 11;
        const int ss = m0 & 2047;
        short4v pv;
        pv[0] = bf16_bits(acc[i][j][0]); pv[1] = bf16_bits(acc[i][j][1]);
        pv[2] = bf16_bits(acc[i][j][2]); pv[3] = bf16_bits(acc[i][j][3]);
        *(short4v*)&vT[((size_t)(bb * 16 + hh) * 128 + dd) * 2048 + ss] = pv;
      }
  } else {
#pragma unroll
    for (int i = 0; i < 4; ++i)
#pragma unroll
      for (int j = 0; j < 4; ++j)
#pragma unroll
        for (int r = 0; r < 4; ++r) {
          const int row = tm + wm + i * 16 + quad * 4 + r;
          const int col = tn + wn + j * 16 + lrow;
          store_c(&C[(size_t)row * ldc + col], acc[i][j][r]);
        }
  }
}

// ---------------------------------------------------------------------------
// RoPE sin/cos table: tab[s*16+i] = (sin(s*inv_i), cos(s*inv_i)).
// Bit-identical math to the former in-rope powf/sincosf.
// ---------------------------------------------------------------------------
__global__ __launch_bounds__(256) void rope_table_kernel(float2* __restrict__ tab) {
  const int idx = blockIdx.x * 256 + threadIdx.x;  // 32768 = 2048 s x 16 i
  const int i = idx & 15;
  const int s = idx >> 4;
  const float inv = powf(10000.f, -(float)(2 * i) / 32.f);
  const float ang = (float)s * inv;
  float sn, cs;
  sincosf(ang, &sn, &cs);
  tab[idx] = make_float2(sn, cs);
}

// ---------------------------------------------------------------------------
// RoPE, in-place on bf16 qkv, table-driven. One thread per (b,s,h,q/k,pair).
// ---------------------------------------------------------------------------
__global__ void rope_kernel(bf16* __restrict__ qkv, const float2* __restrict__ tab) {
  const int idx = blockIdx.x * 256 + threadIdx.x;
  const int i = idx & 15;
  int t = idx >> 4;
  const int qk = t & 1;
  t >>= 1;
  const int h = t & 15;
  t >>= 4;
  const int s = t & 2047;
  bf16* p = qkv + (size_t)t * 6144 + (h >> 1) * 768 + (h & 1) * 128 + qk * 256 + 2 * i;
  const float x0 = __bfloat162float(p[0]);
  const float x1 = __bfloat162float(p[1]);
  const float2 sc2 = tab[(s << 4) + i];
  p[0] = __float2bfloat16(x0 * sc2.y - x1 * sc2.x);
  p[1] = __float2bfloat16(x1 * sc2.y + x0 * sc2.x);
}

// ---------------------------------------------------------------------------
// Flash attention — r8 version, frozen (passed at 116.6 us).
// Swapped-operand S^T/O^T structure, BK=128, global_load_lds staging,
// deferred l-reduction, exact skip-rescale, pre-transposed V from GEMM1.
// Grid (8,16,2); phases qb = bx then 15-bx -> uniform 17 iters per block.
// ---------------------------------------------------------------------------
__global__ __launch_bounds__(256) void attn_flash_pair(
    const bf16* __restrict__ qkv, const bf16* __restrict__ vT,
    bf16* __restrict__ out) {
  __shared__ short Ks[16 * 128 * 8];  // [dgrp 16][key 128][8]   32 KB
  __shared__ short Vs[16 * 128 * 8];  // [kgrp 16][d 128][8]     32 KB
  __shared__ short Ps[16 * 128 * 8];  // [kgrp 16][qrow 128][8]  32 KB
  const int tid = threadIdx.x;
  const int wave = tid >> 6;
  const int lane = tid & 63;
  const int lq = lane & 15;   // q index within 16-tile
  const int quad = lane >> 4;
  const int h = blockIdx.y;
  const int b = blockIdx.z;
  const size_t SROW = 6144;
  const bf16* base = qkv + (size_t)b * 2048 * SROW;
  const bf16* vbase = vT + (size_t)(b * 16 + h) * 262144;
  const int qoff = (h >> 1) * 768 + (h & 1) * 128;
  const int koff = qoff + 256;
  const float scale = 0.088388347648318447f;  // 1/sqrt(128)

  for (int phase = 0; phase < 2; ++phase) {
    const int qb = phase ? (15 - (int)blockIdx.x) : (int)blockIdx.x;

    // Q B-frags: q-col = lane&15, k = quad*8+j (r5-proven load).
    short8 qf[2][4];
#pragma unroll
    for (int rt = 0; rt < 2; ++rt) {
      const bf16* qp =
          base + (size_t)(qb * 128 + wave * 32 + rt * 16 + lq) * SROW + qoff + quad * 8;
#pragma unroll
      for (int ks = 0; ks < 4; ++ks) qf[rt][ks] = *(const short8*)(qp + ks * 32);
    }

    floatx4 o[2][8] = {};
    float m_i[2] = {-1e30f, -1e30f};
    float l_acc[2] = {0.f, 0.f};

    const int kb_end = qb + 1;  // 128-key blocks overlapping tril
    for (int kb = 0; kb < kb_end; ++kb) {
      __syncthreads();  // all waves done reading Ks/Vs/Ps of previous iter

      // Stage K and V tiles via global_load_lds: 8+8 instrs per wave.
#pragma unroll
      for (int i = 0; i < 8; ++i) {
        const int u = wave * 8 + i;
        const int g = u >> 1;
        const int half = (u & 1) * 64;
        __builtin_amdgcn_global_load_lds(
            (const __attribute__((address_space(1))) void*)(
                base + (size_t)(kb * 128 + half + lane) * SROW + koff + g * 8),
            (__attribute__((address_space(3))) void*)(Ks + (g * 128 + half + lane) * 8),
            16, 0, 0);
        __builtin_amdgcn_global_load_lds(
            (const __attribute__((address_space(1))) void*)(
                vbase + (size_t)(half + lane) * 2048 + kb * 128 + g * 8),
            (__attribute__((address_space(3))) void*)(Vs + (g * 128 + half + lane) * 8),
            16, 0, 0);
      }
      __syncthreads();  // compiler drains vmcnt before the barrier (m97 pattern)

      // S^T = K Q : sc[rt][ct][r] = S_raw[key = kb*128+ct*16+quad*4+r][q]
      floatx4 sc[2][8] = {};
      __builtin_amdgcn_s_setprio(1);
#pragma unroll
      for (int ks = 0; ks < 4; ++ks) {
        const int dg = ks * 4 + quad;
        short8 kf[8];
#pragma unroll
        for (int ct = 0; ct < 8; ++ct)
          kf[ct] = *(const short8*)&Ks[(dg * 128 + ct * 16 + lq) * 8];
#pragma unroll
        for (int rt = 0; rt < 2; ++rt)
#pragma unroll
          for (int ct = 0; ct < 8; ++ct)
            sc[rt][ct] = MFMA_BF16(kf[ct], qf[rt][ks], sc[rt][ct]);
      }
      __builtin_amdgcn_s_setprio(0);

      // causal mask (diag iter only) + online softmax per q (raw domain,
      // scale folded into exp args; l shuffles deferred to epilogue).
      const int qrow0 = qb * 128 + wave * 32;
      const bool diag = (kb == qb);  // block-uniform
#pragma unroll
      for (int rt = 0; rt < 2; ++rt) {
        const int qg = qrow0 + rt * 16 + lq;
        if (diag) {
#pragma unroll
          for (int ct = 0; ct < 8; ++ct)
#pragma unroll
            for (int r = 0; r < 4; ++r)
              if (kb * 128 + ct * 16 + quad * 4 + r > qg) sc[rt][ct][r] = -1e9f;
        }
        float cm[8];
#pragma unroll
        for (int ct = 0; ct < 8; ++ct)
          cm[ct] = fmaxf(fmaxf(sc[rt][ct][0], sc[rt][ct][1]),
                         fmaxf(sc[rt][ct][2], sc[rt][ct][3]));
        float mx = fmaxf(fmaxf(fmaxf(cm[0], cm[1]), fmaxf(cm[2], cm[3])),
                         fmaxf(fmaxf(cm[4], cm[5]), fmaxf(cm[6], cm[7])));
        mx = fmaxf(mx, __shfl_xor(mx, 16, 64));
        mx = fmaxf(mx, __shfl_xor(mx, 32, 64));
        float mcur = m_i[rt];
        if (!__all(mx <= mcur)) {  // exact skip: alpha==1 when max unchanged
          const float mnew = fmaxf(mcur, mx);
          const float alpha = __expf((mcur - mnew) * scale);
          m_i[rt] = mnew;
          mcur = mnew;
          l_acc[rt] *= alpha;
#pragma unroll
          for (int dt = 0; dt < 8; ++dt) o[rt][dt] *= alpha;
        }
        float s0 = 0.f, s1 = 0.f, s2 = 0.f, s3 = 0.f;
#pragma unroll
        for (int ct = 0; ct < 8; ++ct) {
          const float p0 = __expf((sc[rt][ct][0] - mcur) * scale);
          const float p1 = __expf((sc[rt][ct][1] - mcur) * scale);
          const float p2 = __expf((sc[rt][ct][2] - mcur) * scale);
          const float p3 = __expf((sc[rt][ct][3] - mcur) * scale);
          sc[rt][ct][0] = p0; sc[rt][ct][1] = p1; sc[rt][ct][2] = p2; sc[rt][ct][3] = p3;
          s0 += p0; s1 += p1; s2 += p2; s3 += p3;
        }
        l_acc[rt] += (s0 + s1) + (s2 + s3);  // per-quad partial; reduced at end
        // P pack + b64 store: keys ct*16 + quad*4 + (0..3) of q-row `prow`.
        const int prow = wave * 32 + rt * 16 + lq;
#pragma unroll
        for (int ct = 0; ct < 8; ++ct) {
          short4v pv;
          pv[0] = bf16_bits(sc[rt][ct][0]); pv[1] = bf16_bits(sc[rt][ct][1]);
          pv[2] = bf16_bits(sc[rt][ct][2]); pv[3] = bf16_bits(sc[rt][ct][3]);
          const int kgrp = ct * 2 + (quad >> 1);
          *(short4v*)&Ps[(kgrp * 128 + prow) * 8 + (quad & 1) * 4] = pv;
        }
      }

      // O^T += V P : o[rt][dt] rows = d (quad*4+r), cols = q (lane&15).
      // Same-wave LDS RAW on Ps (each wave reads only its own 32 q-rows).
      __builtin_amdgcn_s_setprio(1);
#pragma unroll
      for (int kk = 0; kk < 4; ++kk) {
        short8 pf[2], vf[8];
#pragma unroll
        for (int rt = 0; rt < 2; ++rt)
          pf[rt] = *(const short8*)&Ps[((kk * 4 + quad) * 128 + wave * 32 + rt * 16 + lq) * 8];
#pragma unroll
        for (int dt = 0; dt < 8; ++dt)
          vf[dt] = *(const short8*)&Vs[((kk * 4 + quad) * 128 + dt * 16 + lq) * 8];
#pragma unroll
        for (int rt = 0; rt < 2; ++rt)
#pragma unroll
          for (int dt = 0; dt < 8; ++dt)
            o[rt][dt] = MFMA_BF16(vf[dt], pf[rt], o[rt][dt]);
      }
      __builtin_amdgcn_s_setprio(0);
    }

    // epilogue: reduce per-quad l partials (deferred shuffles), store O^T/l.
#pragma unroll
    for (int rt = 0; rt < 2; ++rt) {
      float l = l_acc[rt];
      l += __shfl_xor(l, 16, 64);
      l += __shfl_xor(l, 32, 64);
      const float inv_l = 1.f / l;
      const int qg = qb * 128 + wave * 32 + rt * 16 + lq;
      bf16* op = out + ((size_t)(b * 2048 + qg)) * 2048 + h * 128 + quad * 4;
#pragma unroll
      for (int dt = 0; dt < 8; ++dt) {
        short4v s4;
        s4[0] = bf16_bits(o[rt][dt][0] * inv_l);
        s4[1] = bf16_bits(o[rt][dt][1] * inv_l);
        s4[2] = bf16_bits(o[rt][dt][2] * inv_l);
        s4[3] = bf16_bits(o[rt][dt][3] * inv_l);
        *(short4v*)(op + dt * 16) = s4;
      }
    }
  }
}

// ---------------------------------------------------------------------------
// Workspace budget:
//   d_ws:  [0, 48 MiB)  qkv (v-slots unused); after attn the region is dead
//          and its first 8 MiB is reused for Wout in bf16.
//          [48, 64 MiB) flex: W_qkv half -> rope table (256 KB) -> attnout.
//   d_out: [0, 16 MiB)  hidden_bf16 scratch (dead before GEMM2 rewrites)
//          [16, 32 MiB) vT (b,h,d,s) bf16 — written by GEMM1, read by attn,
//          dead before GEMM2 writes outp.
// ---------------------------------------------------------------------------
extern "C" void kernel_launch(void* const* d_in, const int* in_sizes, int n_in,
                              void* d_out, int out_size, void* d_ws, size_t ws_size,
                              hipStream_t stream) {
  const float* hidden = (const float*)d_in[0];  // (2,2048,2048) f32
  const float* Wqkv = (const float*)d_in[1];    // (6144,2048)  f32
  const float* Wout = (const float*)d_in[2];    // (2048,2048)  f32
  float* outp = (float*)d_out;                  // (2,2048,2048) f32

  bf16* qkv = (bf16*)d_ws;                    // 48 MiB
  bf16* flex = qkv + (size_t)4096 * 6144;     // 16 MiB flex
  bf16* hbf = (bf16*)d_out;                   // d_out scratch, 16 MiB
  bf16* vT = (bf16*)d_out + (size_t)8 * 1024 * 1024;  // d_out[16,32 MiB)
  bf16* woutbf = qkv;                         // qkv region, dead after attn
  float2* tab = (float2*)flex;                // 256 KB, dead after rope

  f32_to_bf16_kernel<<<4096, 256, 0, stream>>>(hidden, hbf, 1048576);

  f32_to_bf16_kernel<<<3072, 256, 0, stream>>>(Wqkv, flex, 786432);
  gemm_bt_async<bf16><<<dim3(24, 32), 256, 0, stream>>>(hbf, flex, qkv, 6144, 2048, vT, 0);
  f32_to_bf16_kernel<<<3072, 256, 0, stream>>>(Wqkv + (size_t)3072 * 2048, flex, 786432);
  gemm_bt_async<bf16><<<dim3(24, 32), 256, 0, stream>>>(hbf, flex, qkv + 3072, 6144, 2048, vT, 8);

  rope_table_kernel<<<128, 256, 0, stream>>>(tab);
  rope_kernel<<<8192, 256, 0, stream>>>(qkv, tab);

  bf16* attnout = flex;
  attn_flash_pair<<<dim3(8, 16, 2), 256, 0, stream>>>(qkv, vT, attnout);

  // Out-projection: convert Wout to bf16 (qkv region is dead now) and run the
  // pure-bf16 m97-structure GEMM (gload_lds both operands) instead of the
  // mixed f32-B kernel.
  f32_to_bf16_kernel<<<2048, 256, 0, stream>>>(Wout, woutbf, 524288);
  gemm_bt_async<float><<<dim3(16, 32), 256, 0, stream>>>(attnout, woutbf, outp, 2048, 2048,
                                                         (bf16*)nullptr, 0);
}